// Round 4
// baseline (1343.073 us; speedup 1.0000x reference)
//
#include <hip/hip_runtime.h>
#include <hip/hip_bf16.h>

#define NPTS 1000000
#define NSEG 4096

// 4 rows x 4 cols register-tile GEMM: acc[i][j] = sum_k x_i[k] * Wl[k][cg*4+j]
__device__ __forceinline__ void gemm_tile(
    const float* __restrict__ Wl,
    const float* __restrict__ xr0, const float* __restrict__ xr1,
    const float* __restrict__ xr2, const float* __restrict__ xr3,
    int cg, float acc[4][4]) {
#pragma unroll
  for (int i = 0; i < 4; ++i)
#pragma unroll
    for (int j = 0; j < 4; ++j) acc[i][j] = 0.f;
#pragma unroll 4
  for (int k4 = 0; k4 < 32; ++k4) {
    float4 a0 = *(const float4*)(xr0 + k4 * 4);
    float4 a1 = *(const float4*)(xr1 + k4 * 4);
    float4 a2 = *(const float4*)(xr2 + k4 * 4);
    float4 a3 = *(const float4*)(xr3 + k4 * 4);
#pragma unroll
    for (int kk = 0; kk < 4; ++kk) {
      float4 bv = *(const float4*)(Wl + (k4 * 4 + kk) * 128 + cg * 4);
      float e0 = ((const float*)&a0)[kk];
      float e1 = ((const float*)&a1)[kk];
      float e2 = ((const float*)&a2)[kk];
      float e3 = ((const float*)&a3)[kk];
      acc[0][0] += e0 * bv.x; acc[0][1] += e0 * bv.y; acc[0][2] += e0 * bv.z; acc[0][3] += e0 * bv.w;
      acc[1][0] += e1 * bv.x; acc[1][1] += e1 * bv.y; acc[1][2] += e1 * bv.z; acc[1][3] += e1 * bv.w;
      acc[2][0] += e2 * bv.x; acc[2][1] += e2 * bv.y; acc[2][2] += e2 * bv.z; acc[2][3] += e2 * bv.w;
      acc[3][0] += e3 * bv.x; acc[3][1] += e3 * bv.y; acc[3][2] += e3 * bv.z; acc[3][3] += e3 * bv.w;
    }
  }
}

// One fully self-contained block per segment. No d_ws, no dynamic LDS.
__global__ __launch_bounds__(256) void k_all(
    const float* __restrict__ x, const float* __restrict__ wp,
    const float* __restrict__ Wc, const float* __restrict__ bc,
    const float* __restrict__ Wa,
    const float* __restrict__ gamma, const float* __restrict__ beta,
    const void* __restrict__ seg, float* __restrict__ out) {

  __shared__ float Wl[16384];   // 64 KB static; transiently aliased for reductions

  const int t = threadIdx.x;
  const int s = blockIdx.x;
  const int* seg32 = (const int*)seg;

  // ---- detect int64 vs int32 segment_idx (contract says int32; be safe) ----
  if (t == 0) ((int*)Wl)[0] = 0;
  __syncthreads();
  {
    int any = 0;
#pragma unroll
    for (int k = 0; k < 16; ++k) any |= seg32[2 * (t * 16 + k) + 1];
    if (any) ((int*)Wl)[0] = 1;     // benign race: all writers store 1
  }
  __syncthreads();
  const int f64 = (((int*)Wl)[0] == 0);   // all high words zero => int64
  __syncthreads();

  // ---- binary search segment range [start, end) ----
  int lo = 0, hi = NPTS;
  while (lo < hi) {
    int mid = (lo + hi) >> 1;
    int v = f64 ? (int)((const long long*)seg)[mid] : seg32[mid];
    if (v < s) lo = mid + 1; else hi = mid;
  }
  const int start = lo;
  hi = NPTS;
  while (lo < hi) {
    int mid = (lo + hi) >> 1;
    int v = f64 ? (int)((const long long*)seg)[mid] : seg32[mid];
    if (v < s + 1) lo = mid + 1; else hi = mid;
  }
  const int end = lo;
  if (start >= end) return;      // uniform across block; no barriers skipped

  // ---- load W (128x128 f32) into LDS ----
  {
    const float4* src = (const float4*)Wc;
    float4* dst = (float4*)Wl;
    for (int i = t; i < 4096; i += 256) dst[i] = src[i];
  }
  __syncthreads();

  // ---- u = Wc . Wa  (att projection; additive bias cancels in softmax) ----
  float uval = 0.f;
  if (t < 128) {
    const float4* wa4 = (const float4*)Wa;
#pragma unroll 8
    for (int c4 = 0; c4 < 32; ++c4) {
      float4 wl = *(const float4*)(Wl + t * 128 + c4 * 4);
      float4 wv = wa4[c4];
      uval += wl.x * wv.x + wl.y * wv.y + wl.z * wv.z + wl.w * wv.w;
    }
  }
  __syncthreads();
  if (t < 128) Wl[t] = uval;     // alias row 0 with u[]
  __syncthreads();
  const int q8 = t & 7;          // octet lane
  const int sr = (t & 31) >> 3;  // subrow within half-wave
  const int cg = t & 31;         // channel group (4 ch each)
  const int rg = t >> 5;         // row group (4 rows each)
  float ur[16];
#pragma unroll
  for (int j = 0; j < 16; ++j) ur[j] = Wl[q8 * 16 + j];
  __syncthreads();
  if (t < 32) ((float4*)Wl)[t] = ((const float4*)Wc)[t];   // restore row 0
  __syncthreads();

  // ---- pass A: online softmax stats (max, sum e, sum e*wp) ----
  float m = -3.0e38f, se = 0.f, sw = 0.f;
  for (int row0 = start; row0 < end; row0 += 32) {
    int row = row0 + rg * 4 + sr;
    int ra = row < NPTS ? row : NPTS - 1;
    const float4* xp = (const float4*)(x + (size_t)ra * 128 + q8 * 16);
    float4 a0 = xp[0], b0 = xp[1], c0 = xp[2], d0 = xp[3];
    float av = a0.x*ur[0] + a0.y*ur[1] + a0.z*ur[2] + a0.w*ur[3]
             + b0.x*ur[4] + b0.y*ur[5] + b0.z*ur[6] + b0.w*ur[7]
             + c0.x*ur[8] + c0.y*ur[9] + c0.z*ur[10]+ c0.w*ur[11]
             + d0.x*ur[12]+ d0.y*ur[13]+ d0.z*ur[14]+ d0.w*ur[15];
    av += __shfl_xor(av, 1, 64);
    av += __shfl_xor(av, 2, 64);
    av += __shfl_xor(av, 4, 64);          // all 8 octet lanes: full dot
    if (row < end) {
      float w = wp[row];
      float nm = fmaxf(m, av);
      float sc = __expf(m - nm);
      float e  = __expf(av - nm);
      se = se * sc + e;
      sw = sw * sc + e * w;
      m = nm;
    }
  }
  // combine 32 octet-leader states (alias Wl[0..95])
  __syncthreads();
  if (q8 == 0) { int lid = t >> 3; Wl[lid] = m; Wl[32 + lid] = se; Wl[64 + lid] = sw; }
  __syncthreads();
  float gmx = -3.0e38f, gse = 0.f, gsw = 0.f;
  for (int i = 0; i < 32; ++i) {
    float mi = Wl[i], sei = Wl[32 + i], swi = Wl[64 + i];
    float nm = fmaxf(gmx, mi);
    float s1 = __expf(gmx - nm), s2 = __expf(mi - nm);
    gse = gse * s1 + sei * s2;
    gsw = gsw * s1 + swi * s2;
    gmx = nm;
  }
  __syncthreads();
  if (t < 24) ((float4*)Wl)[t] = ((const float4*)Wc)[t];   // restore Wl[0..95]
  __syncthreads();
  const float ratio = gsw / gse;
  const float dn    = fmaxf(ratio, 1e-3f);
  const float ka    = 1.0f / (gse * dn);
  const float Sa    = ratio / dn;
  const float maxv  = gmx;

  float bias4[4];
  *(float4*)bias4 = *(const float4*)(bc + cg * 4);

  // ---- pass C: GEMM + weighted stats + 'a' output ----
  float macc[4] = {0.f,0.f,0.f,0.f}, m2cc[4] = {0.f,0.f,0.f,0.f};
  for (int row0 = start; row0 < end; row0 += 32) {
    int r0 = row0 + rg * 4;
    const float* xr[4];
#pragma unroll
    for (int i = 0; i < 4; ++i) {
      int row = r0 + i;
      xr[i] = x + (size_t)(row < NPTS ? row : NPTS - 1) * 128;
    }
    float acc[4][4];
    gemm_tile(Wl, xr[0], xr[1], xr[2], xr[3], cg, acc);

    // attention weight for this block-tile's rows (octet scheme)
    int rowa = r0 + sr;
    int ra = rowa < NPTS ? rowa : NPTS - 1;
    const float4* xp = (const float4*)(x + (size_t)ra * 128 + q8 * 16);
    float4 a0 = xp[0], b0 = xp[1], c0 = xp[2], d0 = xp[3];
    float av = a0.x*ur[0] + a0.y*ur[1] + a0.z*ur[2] + a0.w*ur[3]
             + b0.x*ur[4] + b0.y*ur[5] + b0.z*ur[6] + b0.w*ur[7]
             + c0.x*ur[8] + c0.y*ur[9] + c0.z*ur[10]+ c0.w*ur[11]
             + d0.x*ur[12]+ d0.y*ur[13]+ d0.z*ur[14]+ d0.w*ur[15];
    av += __shfl_xor(av, 1, 64);
    av += __shfl_xor(av, 2, 64);
    av += __shfl_xor(av, 4, 64);
    float a_row = __expf(av - maxv) * wp[ra] * ka;
    if (q8 == 0 && rowa < end) out[(size_t)NPTS * 128 + rowa] = a_row;

    float aw[4];
#pragma unroll
    for (int i = 0; i < 4; ++i) {
      float v = __shfl(a_row, (t & 32) + i * 8, 64);
      aw[i] = (r0 + i < end) ? v : 0.f;
    }
#pragma unroll
    for (int i = 0; i < 4; ++i) {
      float a = aw[i];
#pragma unroll
      for (int j = 0; j < 4; ++j) {
        float h = acc[i][j] + bias4[j];
        macc[j] += a * h;
        m2cc[j] += a * h * h;
      }
    }
  }

  // ---- cross-wave stats reduce (alias Wl[0..1023]) ----
  __syncthreads();
  *(float4*)(Wl + rg * 128 + cg * 4) = make_float4(macc[0], macc[1], macc[2], macc[3]);
  __syncthreads();
  float mean[4] = {0.f,0.f,0.f,0.f};
#pragma unroll
  for (int g = 0; g < 8; ++g) {
    float4 v = *(const float4*)(Wl + g * 128 + cg * 4);
    mean[0] += v.x; mean[1] += v.y; mean[2] += v.z; mean[3] += v.w;
  }
  __syncthreads();
  *(float4*)(Wl + rg * 128 + cg * 4) = make_float4(m2cc[0], m2cc[1], m2cc[2], m2cc[3]);
  __syncthreads();
  float isd[4];
  {
    float M2[4] = {0.f,0.f,0.f,0.f};
#pragma unroll
    for (int g = 0; g < 8; ++g) {
      float4 v = *(const float4*)(Wl + g * 128 + cg * 4);
      M2[0] += v.x; M2[1] += v.y; M2[2] += v.z; M2[3] += v.w;
    }
#pragma unroll
    for (int j = 0; j < 4; ++j) {
      float var = M2[j] - mean[j] * mean[j] * (2.f - Sa);
      isd[j] = 1.0f / sqrtf(var + 1e-3f);
    }
  }
  __syncthreads();
  ((float4*)Wl)[t] = ((const float4*)Wc)[t];   // restore Wl[0..1023]
  __syncthreads();

  float g4[4], b4[4];
  *(float4*)g4 = *(const float4*)(gamma + cg * 4);
  *(float4*)b4 = *(const float4*)(beta  + cg * 4);

  // ---- pass D: GEMM + ACN normalize + GroupNorm + ReLU + store (f32) ----
  for (int row0 = start; row0 < end; row0 += 32) {
    int r0 = row0 + rg * 4;
    const float* xr[4];
#pragma unroll
    for (int i = 0; i < 4; ++i) {
      int row = r0 + i;
      xr[i] = x + (size_t)(row < NPTS ? row : NPTS - 1) * 128;
    }
    float acc[4][4];
    gemm_tile(Wl, xr[0], xr[1], xr[2], xr[3], cg, acc);
#pragma unroll
    for (int i = 0; i < 4; ++i) {
      int row = r0 + i;
      if (row < end) {
        float o[4];
#pragma unroll
        for (int j = 0; j < 4; ++j) o[j] = (acc[i][j] + bias4[j] - mean[j]) * isd[j];
        float mu  = 0.25f * (o[0] + o[1] + o[2] + o[3]);
        float msq = 0.25f * (o[0]*o[0] + o[1]*o[1] + o[2]*o[2] + o[3]*o[3]);
        float gs  = 1.0f / sqrtf(msq - mu * mu + 1e-5f);
        float r0v = fmaxf((o[0] - mu) * gs * g4[0] + b4[0], 0.f);
        float r1v = fmaxf((o[1] - mu) * gs * g4[1] + b4[1], 0.f);
        float r2v = fmaxf((o[2] - mu) * gs * g4[2] + b4[2], 0.f);
        float r3v = fmaxf((o[3] - mu) * gs * g4[3] + b4[3], 0.f);
        *(float4*)(out + (size_t)row * 128 + cg * 4) = make_float4(r0v, r1v, r2v, r3v);
      }
    }
  }
}

extern "C" void kernel_launch(void* const* d_in, const int* in_sizes, int n_in,
                              void* d_out, int out_size, void* d_ws, size_t ws_size,
                              hipStream_t stream) {
  // setup_inputs() dict order:
  // 0:x 1:weight_pri 2:W_conv 3:b_conv 4:W_att 5:b_att 6:gamma 7:beta 8:segment_idx
  const float* x    = (const float*)d_in[0];
  const float* wpri = (const float*)d_in[1];
  const float* Wc   = (const float*)d_in[2];
  const float* bc   = (const float*)d_in[3];
  const float* Wa   = (const float*)d_in[4];
  const float* gm   = (const float*)d_in[6];
  const float* bt   = (const float*)d_in[7];
  const void*  seg  = d_in[8];
  float* out = (float*)d_out;

  (void)d_ws; (void)ws_size; (void)in_sizes; (void)n_in; (void)out_size;

  k_all<<<NSEG, 256, 0, stream>>>(x, wpri, Wc, bc, Wa, gm, bt, seg, out);
}